// Round 5
// baseline (488.325 us; speedup 1.0000x reference)
//
#include <hip/hip_runtime.h>

// HMM forward: B=64, T=512, S=35, D=2496.
// emis: bf16 MFMA GEMM, NO LDS / NO BARRIERS. Unified chunk-granular FIFO,
//       depth 8 (40 loads, 640 B/wave in flight = 5.1 KB/CU @ 2 waves/SIMD):
//       each chunk's {2x A dwordx4, 3x B dwordx4} issued exactly 8 chunks
//       ahead through 8 statically-named buffers -> all waits counted vmcnt,
//       never a drain.
// forward: linear-space recursion p' = E_t (A p), DPP reductions,
//       group-level (8-step) stabilizer, wave_shr:1 DPP rotations.
//       Issue(~440cy) ~= chain(~440cy) -> structural floor, frozen.
//
// SESSION LOG:
// r0: 522 us. Theory: ~394us = harness poison-fills (in-graph), ours ~120us.
// r1: 493.5 us (group stabilizer + DPP rotate + cvt_pk). Fills confirmed.
// r2: 491.1 us. Deep A-prefetch null -> vmcnt in-order drain via interleaved
//     B loads diagnosed.
// r3: 486.2 us. Chunk-FIFO depth 6 (-4.9us, matched prediction). Ours ~89us:
//     emis ~63 (5.2 TB/s) vs 52 floor -> still in-flight-limited.
// r4: depth 8 — bench infra failure (container acquisition), no data.
// r5: resubmit depth 8 unchanged. If gain < 3us: depth-saturated -> ROOFLINE.

#define ROWS 32768   // B*T
#define KD   2496
#define NS   35
#define SPAD 48
#define ES   40      // emis row stride (floats)
#define TT   512

typedef short v8s __attribute__((ext_vector_type(8)));
typedef float v4f __attribute__((ext_vector_type(4)));

__device__ __forceinline__ unsigned short f2bf(float f) {
    unsigned u = __builtin_bit_cast(unsigned, f);
    u += 0x7fffu + ((u >> 16) & 1u);   // RNE
    return (unsigned short)(u >> 16);
}

// ---- DPP cross-lane ops (VALU-latency, no LDS pipe) ----
template <int CTRL, int RM>
__device__ __forceinline__ float dppf(float oldv, float v) {
    return __builtin_bit_cast(float, __builtin_amdgcn_update_dpp(
        __builtin_bit_cast(int, oldv), __builtin_bit_cast(int, v),
        CTRL, RM, 0xf, false));
}

__device__ __forceinline__ float wsum63(float v) {
    v += dppf<0x111, 0xf>(0.f, v);   // row_shr:1
    v += dppf<0x112, 0xf>(0.f, v);   // row_shr:2
    v += dppf<0x114, 0xf>(0.f, v);   // row_shr:4
    v += dppf<0x118, 0xf>(0.f, v);   // row_shr:8
    v += dppf<0x142, 0xa>(0.f, v);   // row_bcast:15
    v += dppf<0x143, 0xc>(0.f, v);   // row_bcast:31
    return __builtin_bit_cast(float,
        __builtin_amdgcn_readlane(__builtin_bit_cast(int, v), 63));
}

__device__ __forceinline__ float wmax63(float v) {
    const float NI = -3.0e38f;
    v = fmaxf(v, dppf<0x111, 0xf>(NI, v));
    v = fmaxf(v, dppf<0x112, 0xf>(NI, v));
    v = fmaxf(v, dppf<0x114, 0xf>(NI, v));
    v = fmaxf(v, dppf<0x118, 0xf>(NI, v));
    v = fmaxf(v, dppf<0x142, 0xa>(NI, v));
    v = fmaxf(v, dppf<0x143, 0xc>(NI, v));
    return __builtin_bit_cast(float,
        __builtin_amdgcn_readlane(__builtin_bit_cast(int, v), 63));
}

__device__ __forceinline__ float rlane(float v, int l) {
    return __builtin_bit_cast(float,
        __builtin_amdgcn_readlane(__builtin_bit_cast(int, v), l));
}

// wave_shr:1 — lane i gets lane i-1 (lane 0 keeps old = v). gfx9-family DPP.
__device__ __forceinline__ float shr1(float v) {
    return dppf<0x138, 0xf>(v, v);
}

// v_cvt_pk_bf16_f32: D[15:0]=bf16(lo), D[31:16]=bf16(hi), RNE.
__device__ __forceinline__ int cvtpk(float lo, float hi) {
    int r;
    asm("v_cvt_pk_bf16_f32 %0, %1, %2" : "=v"(r) : "v"(lo), "v"(hi));
    return r;
}

// ---- Prep: bf16-convert obs_matrix (zero-pad to 48 states) + m_sq ----
__global__ __launch_bounds__(256) void prep_kernel(
        const float* __restrict__ m, unsigned short* __restrict__ mb,
        float* __restrict__ msq) {
    int s = blockIdx.x;
    int tid = threadIdx.x;
    float part = 0.f;
    for (int k = tid; k < KD; k += 256) {
        float v = (s < NS) ? m[s * KD + k] : 0.f;
        mb[s * KD + k] = f2bf(v);
        part += v * v;
    }
    __shared__ float red[256];
    red[tid] = part;
    __syncthreads();
    for (int off = 128; off > 0; off >>= 1) {
        if (tid < off) red[tid] += red[tid + off];
        __syncthreads();
    }
    if (tid == 0) msq[s] = red[0];
}

// ---- emis chunk pipeline: statically-named rotating buffers ----
struct Ch { float4 a0, a1; v8s b0, b1, b2; };

__device__ __forceinline__ void issue_ch(Ch& d, const float* xr,
        const unsigned short* mb0, int c) {
    const float* xa = xr + c * 32;
    d.a0 = *(const float4*)&xa[0];
    d.a1 = *(const float4*)&xa[4];
    const unsigned short* mc = mb0 + c * 32;
    d.b0 = *(const v8s*)&mc[0];
    d.b1 = *(const v8s*)&mc[16 * KD];
    d.b2 = *(const v8s*)&mc[32 * KD];
}

__device__ __forceinline__ void comp_ch(const Ch& ch, v4f (&acc)[3], float& sq) {
    const float4 v0 = ch.a0, v1 = ch.a1;
    sq += v0.x * v0.x + v0.y * v0.y + v0.z * v0.z + v0.w * v0.w
        + v1.x * v1.x + v1.y * v1.y + v1.z * v1.z + v1.w * v1.w;
    union { int i4[4]; v8s v; } au;
    au.i4[0] = cvtpk(v0.x, v0.y);
    au.i4[1] = cvtpk(v0.z, v0.w);
    au.i4[2] = cvtpk(v1.x, v1.y);
    au.i4[3] = cvtpk(v1.z, v1.w);
    acc[0] = __builtin_amdgcn_mfma_f32_16x16x32_bf16(au.v, ch.b0, acc[0], 0, 0, 0);
    acc[1] = __builtin_amdgcn_mfma_f32_16x16x32_bf16(au.v, ch.b1, acc[1], 0, 0, 0);
    acc[2] = __builtin_amdgcn_mfma_f32_16x16x32_bf16(au.v, ch.b2, acc[2], 0, 0, 0);
}

// ---- Emission GEMM, barrier-free. Wave = 16 rows x 48 states.
//      78 K-chunks of 32; FIFO depth 8 chunks (40 loads in flight). ----
__global__ __launch_bounds__(256, 2) void emis_kernel(
        const float* __restrict__ x, const unsigned short* __restrict__ mb,
        const float* __restrict__ msq, float* __restrict__ emis) {
    const int tid = threadIdx.x;
    const int lane = tid & 63, w = tid >> 6;
    const int fm = lane & 15, q = lane >> 4;
    const int row0 = blockIdx.x * 64 + w * 16;          // this wave's row tile
    const float* xr = x + (long)(row0 + fm) * KD + q * 8;     // lane A stream
    const unsigned short* mb0 = mb + (long)fm * KD + q * 8;   // lane B stream

    v4f acc[3] = {};
    float sq = 0.f;

    Ch h0, h1, h2, h3, h4, h5, h6, h7;
    issue_ch(h0, xr, mb0, 0);
    issue_ch(h1, xr, mb0, 1);
    issue_ch(h2, xr, mb0, 2);
    issue_ch(h3, xr, mb0, 3);
    issue_ch(h4, xr, mb0, 4);
    issue_ch(h5, xr, mb0, 5);
    issue_ch(h6, xr, mb0, 6);
    issue_ch(h7, xr, mb0, 7);

    int kq = 8;
    for (int j = 0; j < 8; ++j) {        // computes chunks 0..63, issues 8..71
        comp_ch(h0, acc, sq); issue_ch(h0, xr, mb0, kq + 0);
        comp_ch(h1, acc, sq); issue_ch(h1, xr, mb0, kq + 1);
        comp_ch(h2, acc, sq); issue_ch(h2, xr, mb0, kq + 2);
        comp_ch(h3, acc, sq); issue_ch(h3, xr, mb0, kq + 3);
        comp_ch(h4, acc, sq); issue_ch(h4, xr, mb0, kq + 4);
        comp_ch(h5, acc, sq); issue_ch(h5, xr, mb0, kq + 5);
        comp_ch(h6, acc, sq); issue_ch(h6, xr, mb0, kq + 6);
        comp_ch(h7, acc, sq); issue_ch(h7, xr, mb0, kq + 7);
        kq += 8;
    }
    // computes 64..71, issues 72..77
    comp_ch(h0, acc, sq); issue_ch(h0, xr, mb0, 72);
    comp_ch(h1, acc, sq); issue_ch(h1, xr, mb0, 73);
    comp_ch(h2, acc, sq); issue_ch(h2, xr, mb0, 74);
    comp_ch(h3, acc, sq); issue_ch(h3, xr, mb0, 75);
    comp_ch(h4, acc, sq); issue_ch(h4, xr, mb0, 76);
    comp_ch(h5, acc, sq); issue_ch(h5, xr, mb0, 77);
    comp_ch(h6, acc, sq);
    comp_ch(h7, acc, sq);
    // computes 72..77
    comp_ch(h0, acc, sq);
    comp_ch(h1, acc, sq);
    comp_ch(h2, acc, sq);
    comp_ch(h3, acc, sq);
    comp_ch(h4, acc, sq);
    comp_ch(h5, acc, sq);

    // |x_row|^2: lane holds partial over k = q*8 .. ; reduce across q-groups
    float s2 = sq + __shfl_xor(sq, 16, 64);
    s2 += __shfl_xor(s2, 32, 64);        // lane (fm,q): full |x_{row0+fm}|^2
    float xs[4];
#pragma unroll
    for (int rg = 0; rg < 4; ++rg)
        xs[rg] = __shfl(s2, q * 4 + rg, 64);   // xsq of output row q*4+rg

    // D layout: col = lane&15 -> state, row = q*4+reg -> x-row
#pragma unroll
    for (int nt = 0; nt < 3; ++nt) {
        const int st = nt * 16 + fm;
        if (st < NS) {
            const float ms = msq[st];
#pragma unroll
            for (int rg = 0; rg < 4; ++rg) {
                emis[(long)(row0 + q * 4 + rg) * ES + st] =
                    (xs[rg] + ms - 2.f * acc[nt][rg]) * (-1.f / 500.f);
            }
        }
    }
}

// ---- Forward recursion, linear space, 8-deep e-prefetch, group stabilizer ----
__global__ __launch_bounds__(64) void forward_kernel(
        const float* __restrict__ emis, float* __restrict__ out) {
    const int b = blockIdx.x;
    const int j = threadIdx.x;
    const bool act = j < NS;
    const bool is0 = (j == 0), is1 = (j == 1);
    const int jc = act ? j : NS - 1;
    const float LOG2E = 1.4426950408889634f, LN2 = 0.6931471805599453f;
    const float c0 = 0.1f, c1 = 0.8f, c2 = 0.08f, cb = 0.02f / 35.f;
    const float NI = -3.0e38f;

    const float* ebj = emis + (long)b * TT * ES + jc;

    const float e0 = ebj[0];
    const float a0 = (act ? e0 : NI) + ((j == 0) ? 10.f : -10.f);
    float C = wmax63(act ? a0 : NI);
    float p = act ? __builtin_amdgcn_exp2f((a0 - C) * LOG2E) : 0.f;

    float cur[8], nxt[8];
#pragma unroll
    for (int i = 0; i < 8; ++i) cur[i] = ebj[(1 + i) * ES];   // t = 1..8

    for (int g = 0; g < 63; ++g) {
        const int tb = 9 + 8 * g;
#pragma unroll
        for (int i = 0; i < 8; ++i) {
            const int t = tb + i;
            nxt[i] = ebj[(t < TT ? t : TT - 1) * ES];
        }
        // Group stabilizer: one wave-max per 8 steps, fully off the p-chain.
        float mx8 = cur[0];
#pragma unroll
        for (int i = 1; i < 8; ++i) mx8 = fmaxf(mx8, cur[i]);
        const float Kg = wmax63(act ? mx8 : NI);
        float E[8], Eb[8];
#pragma unroll
        for (int i = 0; i < 8; ++i) {
            E[i]  = act ? __builtin_amdgcn_exp2f((cur[i] - Kg) * LOG2E) : 0.f;
            Eb[i] = E[i] * cb;
        }
        float S = 1.f;
#pragma unroll
        for (int i = 0; i < 8; ++i) {
            // rotations (VALU DPP, hidden under wsum chain)
            const float r1 = shr1(p);
            const float r2 = shr1(r1);
            const float p34 = rlane(p, 34), p33 = rlane(p, 33);
            const float pm1 = is0 ? p34 : r1;
            const float pm2 = is0 ? p33 : (is1 ? p34 : r2);
            S = wsum63(p);                                    // chain-dominant
            const float wv = E[i] * fmaf(c1, pm1, fmaf(c2, pm2, c0 * p));
            p = fmaf(Eb[i], S, wv);
        }
        p *= __builtin_amdgcn_rcpf(S);        // bookkeeping renorm (exact-tracked)
        C += 8.f * Kg + LN2 * __builtin_amdgcn_logf(S);
#pragma unroll
        for (int i = 0; i < 8; ++i) cur[i] = nxt[i];
    }
    // tail: t = 505..511 (7 steps)
    float mx7 = cur[0];
#pragma unroll
    for (int i = 1; i < 7; ++i) mx7 = fmaxf(mx7, cur[i]);
    const float Kt = wmax63(act ? mx7 : NI);
#pragma unroll
    for (int i = 0; i < 7; ++i) {
        const float E  = act ? __builtin_amdgcn_exp2f((cur[i] - Kt) * LOG2E) : 0.f;
        const float Eb = E * cb;
        const float r1 = shr1(p);
        const float r2 = shr1(r1);
        const float p34 = rlane(p, 34), p33 = rlane(p, 33);
        const float pm1 = is0 ? p34 : r1;
        const float pm2 = is0 ? p33 : (is1 ? p34 : r2);
        const float S = wsum63(p);
        const float wv = E * fmaf(c1, pm1, fmaf(c2, pm2, c0 * p));
        p = fmaf(Eb, S, wv);
    }
    C += 7.f * Kt;
    const float Sf = wsum63(p);
    if (j == 0) out[b] = C + LN2 * __builtin_amdgcn_logf(Sf);
}

extern "C" void kernel_launch(void* const* d_in, const int* in_sizes, int n_in,
                              void* d_out, int out_size, void* d_ws, size_t ws_size,
                              hipStream_t stream) {
    const float* obs  = (const float*)d_in[0];
    const float* obsm = (const float*)d_in[1];
    float* out = (float*)d_out;

    char* ws = (char*)d_ws;
    float* emis = (float*)ws;                               // 32768*40*4 = 5,242,880 B
    unsigned short* mb = (unsigned short*)(ws + 5242880);   // 48*2496*2  =   239,616 B
    float* msq = (float*)(ws + 5482496);                    // 48*4

    prep_kernel<<<SPAD, 256, 0, stream>>>(obsm, mb, msq);
    emis_kernel<<<ROWS / 64, 256, 0, stream>>>(obs, mb, msq, emis);
    forward_kernel<<<64, 64, 0, stream>>>(emis, out);
}